// Round 9
// baseline (118.959 us; speedup 1.0000x reference)
//
#include <hip/hip_runtime.h>
#include <hip/hip_bf16.h>

#ifndef __has_builtin
#define __has_builtin(x) 0
#endif

#if __has_builtin(__builtin_amdgcn_exp2f)
#define FAST_EXP2(x) __builtin_amdgcn_exp2f(x)
#else
#define FAST_EXP2(x) exp2f(x)
#endif

#if __has_builtin(__builtin_amdgcn_sqrtf)
#define FAST_SQRT(x) __builtin_amdgcn_sqrtf(x)
#else
#define FAST_SQRT(x) sqrtf(x)
#endif

#if __has_builtin(__builtin_amdgcn_fractf)
#define FRACT(x) __builtin_amdgcn_fractf(x)
#else
#define FRACT(x) ((x) - floorf(x))
#endif

// SW exp2(-s) for s >= 0: full-rate ops only (no v_exp_f32).
// 2^-s = 2^-k * 2^-f, k=floor(s), f=fract(s); deg-4 Taylor of 2^-f on [0,1):
// rel err <= 2.7e-3 -> loss error <~8e-4, far under the 6.5e-3 threshold.
// ops: fract, sub, cvt_i32, 4x fma, ldexp = 8 full-rate VALU.
static __device__ __forceinline__ float sw_exp2_neg(float s) {
  float f  = FRACT(s);            // v_fract_f32
  float kf = s - f;               // integer-valued
  int   ki = (int)kf;             // v_cvt_i32_f32 (s>=0 so trunc==floor)
  float poly = fmaf(f, fmaf(f, fmaf(f, fmaf(f, 0.00961813f, -0.05550411f),
                                    0.24022651f), -0.69314718f), 1.0f);
  return ldexpf(poly, -ki);       // v_ldexp_f32; k large -> flush to 0 (correct)
}

// Problem constants (fixed by setup_inputs): B=8, M=N=4096, C=3
constexpr int kB = 8;
constexpr int kM = 4096;
constexpr int kN = 4096;
// softmin: exp(-d/T) = exp2(-C2*d), T=0.1; work in ds = C2*d via C2^2-scaled d^2
constexpr float C2  = 14.426950408889634f;
constexpr float C22 = C2 * C2;
// harness re-poisons d_ws to 0xAA bytes before every launch (stated contract)
#define POISON_U32 0xAAAAAAAAu   // as float: -3.03e-13 (harmless accum base)

constexpr int RPL    = 4;                 // pred rows per lane
constexpr int ROWS   = 64 * RPL;          // 256 rows per block
constexpr int WAVES  = 16;
constexpr int BLOCKT = 64 * WAVES;        // 1024 threads
constexpr int NROWG  = (kB * kM) / ROWS;  // 128 row groups
constexpr int NSPLIT = 4;                 // gt segments across blocks (512 blocks)
// ws layout (tier 1): [0]=accum [1]=ticket [16..]=gt4[kB*kN*4] then partials
constexpr int    PART_OFF  = 16;
constexpr size_t GT4_FLOATS = (size_t)kB * kN * 4;            // 131072
constexpr size_t ws_need_old(int ns) { return (size_t)(PART_OFF + 2 * ns * kB * kM) * 4; }
constexpr size_t WS_NEED_SGPR = (PART_OFF + GT4_FLOATS + (size_t)2 * NSPLIT * kB * kM) * 4;

// ---------------- phase 0: pack gt as (x,y,z, C2^2*|g|^2) ----------------
__global__ __launch_bounds__(256) void emd_prep_kernel(
    const float* __restrict__ gt, float4* __restrict__ gt4) {
  const int i = blockIdx.x * 256 + threadIdx.x;   // < kB*kN
  const float* p = gt + 3 * (size_t)i;
  float x = p[0], y = p[1], z = p[2];
  gt4[i] = make_float4(x, y, z, C22 * fmaf(x, x, fmaf(y, y, z * z)));
}

// ---------------- phase 1: SGPR gt + SW exp2 (trans = sqrt only) ----------------
__global__ __launch_bounds__(BLOCKT, 4) void emd_partial_sgpr(
    const float* __restrict__ pred, const float4* __restrict__ gt4,
    float* __restrict__ partL, float* __restrict__ partA) {
  constexpr int SEGN = kN / NSPLIT;     // 1024 gt points per block
  constexpr int NPC  = SEGN / WAVES;    // 64 gt points per wave
  __shared__ float red_l[WAVES][RPL][64];   // lane-stride 1: conflict-free
  __shared__ float red_a[WAVES][RPL][64];

  const int tid  = threadIdx.x;
  const int lane = tid & 63;
  const int wv   = tid >> 6;
  const int rg   = blockIdx.x / NSPLIT;   // row group
  const int seg  = blockIdx.x % NSPLIT;   // gt segment
  const int rbase = rg * ROWS;
  const int b     = rbase >> 12;          // 256 | 4096 so no batch straddle

  // RPL pred rows per lane (VGPR-resident coefficients)
  float nx[RPL], ny[RPL], nz[RPL], pq[RPL];
  const int m0 = (rbase & (kM - 1)) + lane;
#pragma unroll
  for (int r = 0; r < RPL; ++r) {
    const float* pp = pred + ((size_t)b * kM + m0 + r * 64) * 3;
    float x = pp[0], y = pp[1], z = pp[2];
    nx[r] = -2.0f * C22 * x;
    ny[r] = -2.0f * C22 * y;
    nz[r] = -2.0f * C22 * z;
    pq[r] = C22 * fmaf(x, x, fmaf(y, y, z * z));
  }

  // wave-uniform gt pointer: force wv uniform so the loads scalarize
  const int wvu = __builtin_amdgcn_readfirstlane(wv);
  const float4* __restrict__ gq =
      gt4 + (size_t)b * kN + (size_t)seg * SEGN + (size_t)wvu * NPC;

  // fixed-reference softmin accumulation (d>=0 so exp2(-ds) in (0,1])
  float l[RPL] = {};
  float a[RPL] = {};
  // software pipeline: group of 4 points prefetched one iteration ahead
  float4 c0 = gq[0], c1 = gq[1], c2 = gq[2], c3 = gq[3];
  for (int k = 0; k < NPC; k += 4) {
    const int kn = (k + 4 < NPC) ? k + 4 : 0;   // uniform select (dummy last)
    float4 n0 = gq[kn], n1 = gq[kn + 1], n2 = gq[kn + 2], n3 = gq[kn + 3];
#define BODY(G, r)                                                       \
    {                                                                    \
      float u  = fmaf(nx[r], G.x,                                        \
                 fmaf(ny[r], G.y, fmaf(nz[r], G.z, G.w + pq[r])));       \
      float ds = FAST_SQRT(fmaxf(u, 0.0f));   /* = C2 * d */             \
      float p  = sw_exp2_neg(ds);             /* = exp(-d/T), no trans */\
      l[r] += p;                                                         \
      a[r] = fmaf(ds, p, a[r]);                                          \
    }
#pragma unroll
    for (int r = 0; r < RPL; ++r) BODY(c0, r)
#pragma unroll
    for (int r = 0; r < RPL; ++r) BODY(c1, r)
#pragma unroll
    for (int r = 0; r < RPL; ++r) BODY(c2, r)
#pragma unroll
    for (int r = 0; r < RPL; ++r) BODY(c3, r)
#undef BODY
    c0 = n0; c1 = n1; c2 = n2; c3 = n3;
  }
#pragma unroll
  for (int r = 0; r < RPL; ++r) {
    red_l[wv][r][lane] = l[r];
    red_a[wv][r][lane] = a[r];
  }
  __syncthreads();

  // combine the 16 waves' chunks; one thread per (r, lane) row
  if (tid < 64 * RPL) {
    const int ln = tid & 63, r = tid >> 6;
    float lt = 0.f, at = 0.f;
#pragma unroll
    for (int c = 0; c < WAVES; ++c) { lt += red_l[c][r][ln]; at += red_a[c][r][ln]; }
    const int row = rbase + r * 64 + ln;
    partL[(size_t)seg * (kB * kM) + row] = lt;
    partA[(size_t)seg * (kB * kM) + row] = at;
  }
}

// ---------------- phase 2: per-row divide + global mean ----------------
constexpr int CB      = 512;
constexpr int CBLOCKS = (kB * kM) / CB;   // 64
template <int NSEG>
__global__ __launch_bounds__(CB) void emd_combine_kernel(
    const float* __restrict__ partL, const float* __restrict__ partA,
    float* __restrict__ ws, float* __restrict__ out) {
  const int row = blockIdx.x * CB + threadIdx.x;
  float lt = 0.f, at = 0.f;
#pragma unroll
  for (int s = 0; s < NSEG; ++s) {
    lt += partL[(size_t)s * (kB * kM) + row];
    at += partA[(size_t)s * (kB * kM) + row];
  }
  // at/lt = C2 * softmin-weighted dist; undo C2 and fold the 1/(B*M) mean
  float w = (at / lt) * (1.0f / (C2 * (float)(kB * kM)));
#pragma unroll
  for (int off = 32; off > 0; off >>= 1) w += __shfl_down(w, off, 64);
  __shared__ float sred[CB / 64];
  const int lane = threadIdx.x & 63, wv = threadIdx.x >> 6;
  if (lane == 0) sred[wv] = w;
  __syncthreads();
  if (threadIdx.x == 0) {
    float s = 0.f;
#pragma unroll
    for (int i = 0; i < CB / 64; ++i) s += sred[i];
    // ws[0] starts at poison float(0xAAAAAAAA) = -3.03e-13 (negligible)
    atomicAdd(&ws[0], s);
    __threadfence();
    unsigned t = atomicAdd((unsigned int*)(ws + 1), 1u);
    if (t == POISON_U32 + (unsigned)(CBLOCKS - 1)) {
      __threadfence();
      out[0] = atomicAdd(&ws[0], 0.0f);   // device-coherent read; fp32 output
    }
  }
}

// -------- tier-2 partial (R7 LDS path, proven 42.6 us) if ws too small --------
template <int NS>
__global__ __launch_bounds__(BLOCKT, 4) void emd_partial_lds(
    const float* __restrict__ pred, const float* __restrict__ gt,
    float* __restrict__ partL, float* __restrict__ partA) {
  constexpr int SEGN = kN / NS;
  constexpr int NPC  = SEGN / WAVES;
  __shared__ __align__(16) float4 g4[SEGN];
  __shared__ float red_l[WAVES][RPL][64];
  __shared__ float red_a[WAVES][RPL][64];
  const int tid = threadIdx.x, lane = tid & 63, wv = tid >> 6;
  const int rg = blockIdx.x / NS, seg = blockIdx.x % NS;
  const int rbase = rg * ROWS, b = rbase >> 12;
  const float* gtb = gt + ((size_t)b * kN + (size_t)seg * SEGN) * 3;
  for (int i = tid; i < SEGN; i += BLOCKT) {
    const float* p = gtb + 3 * i;
    float x = p[0], y = p[1], z = p[2];
    g4[i] = make_float4(x, y, z, C22 * fmaf(x, x, fmaf(y, y, z * z)));
  }
  float nx[RPL], ny[RPL], nz[RPL], pq[RPL];
  const int m0 = (rbase & (kM - 1)) + lane;
#pragma unroll
  for (int r = 0; r < RPL; ++r) {
    const float* pp = pred + ((size_t)b * kM + m0 + r * 64) * 3;
    float x = pp[0], y = pp[1], z = pp[2];
    nx[r] = -2.0f * C22 * x; ny[r] = -2.0f * C22 * y; nz[r] = -2.0f * C22 * z;
    pq[r] = C22 * fmaf(x, x, fmaf(y, y, z * z));
  }
  __syncthreads();
  float l[RPL] = {}, a[RPL] = {};
  const int n0 = wv * NPC;
  for (int n = n0; n < n0 + NPC; n += 4) {
    float4 G[4];
#pragma unroll
    for (int j = 0; j < 4; ++j) G[j] = g4[n + j];
#pragma unroll
    for (int j = 0; j < 4; ++j)
#pragma unroll
      for (int r = 0; r < RPL; ++r) {
        float u  = fmaf(nx[r], G[j].x,
                   fmaf(ny[r], G[j].y, fmaf(nz[r], G[j].z, G[j].w + pq[r])));
        float ds = FAST_SQRT(fmaxf(u, 0.0f));
        float p  = FAST_EXP2(-ds);
        l[r] += p; a[r] = fmaf(ds, p, a[r]);
      }
  }
#pragma unroll
  for (int r = 0; r < RPL; ++r) { red_l[wv][r][lane] = l[r]; red_a[wv][r][lane] = a[r]; }
  __syncthreads();
  if (tid < 64 * RPL) {
    const int ln = tid & 63, r = tid >> 6;
    float lt = 0.f, at = 0.f;
#pragma unroll
    for (int c = 0; c < WAVES; ++c) { lt += red_l[c][r][ln]; at += red_a[c][r][ln]; }
    const int row = rbase + r * 64 + ln;
    partL[(size_t)seg * (kB * kM) + row] = lt;
    partA[(size_t)seg * (kB * kM) + row] = at;
  }
}

// ---------------- tier-3 mono-kernel fallback (proven R3) ----------------
constexpr int F_CHUNKS = 16, F_BLOCKT = 64 * F_CHUNKS;
constexpr int F_NPC = kN / F_CHUNKS, F_NBLOCKS = (kB * kM) / 64;
__global__ __launch_bounds__(F_BLOCKT, 8) void emd_softmin_fallback(
    const float* __restrict__ pred, const float* __restrict__ gt,
    float* __restrict__ ws, float* __restrict__ out) {
  __shared__ __align__(16) float4 g4[kN];
  __shared__ float red_l[F_CHUNKS][64];
  __shared__ float red_a[F_CHUNKS][64];
  const int tid = threadIdx.x, lane = tid & 63, chunk = tid >> 6;
  const int rbase = blockIdx.x * 64, b = rbase >> 12, m = (rbase & (kM - 1)) + lane;
  const float* gtb = gt + (size_t)b * kN * 3;
  for (int i = tid; i < kN; i += F_BLOCKT) {
    const float* p = gtb + 3 * i;
    float x = p[0], y = p[1], z = p[2];
    g4[i] = make_float4(x, y, z, C22 * fmaf(x, x, fmaf(y, y, z * z)));
  }
  const float* pp = pred + ((size_t)b * kM + (size_t)m) * 3;
  const float px = pp[0], py = pp[1], pz = pp[2];
  const float nx = -2.0f * C22 * px, ny = -2.0f * C22 * py, nz = -2.0f * C22 * pz;
  const float pq = C22 * fmaf(px, px, fmaf(py, py, pz * pz));
  __syncthreads();
  float l0 = 0.f, l1 = 0.f, a0 = 0.f, a1 = 0.f;
  const int n0 = chunk * F_NPC;
#pragma unroll 2
  for (int n = n0; n < n0 + F_NPC; n += 2) {
    const float4 G0 = g4[n], G1 = g4[n + 1];
    { float u = fmaf(nx, G0.x, fmaf(ny, G0.y, fmaf(nz, G0.z, G0.w + pq)));
      float ds = FAST_SQRT(fmaxf(u, 0.f)); float p = FAST_EXP2(-ds);
      l0 += p; a0 = fmaf(ds, p, a0); }
    { float u = fmaf(nx, G1.x, fmaf(ny, G1.y, fmaf(nz, G1.z, G1.w + pq)));
      float ds = FAST_SQRT(fmaxf(u, 0.f)); float p = FAST_EXP2(-ds);
      l1 += p; a1 = fmaf(ds, p, a1); }
  }
  red_l[chunk][lane] = l0 + l1; red_a[chunk][lane] = a0 + a1;
  __syncthreads();
  if (tid < 64) {
    float lt = 0.f, at = 0.f;
#pragma unroll
    for (int c = 0; c < F_CHUNKS; ++c) { lt += red_l[c][tid]; at += red_a[c][tid]; }
    float w = (at / lt) * (1.0f / (C2 * (float)(kB * kM)));
#pragma unroll
    for (int off = 32; off > 0; off >>= 1) w += __shfl_down(w, off, 64);
    if (tid == 0) {
      atomicAdd(&ws[0], w);
      __threadfence();
      unsigned t = atomicAdd((unsigned int*)(ws + 1), 1u);
      if (t == POISON_U32 + (unsigned)(F_NBLOCKS - 1)) {
        __threadfence();
        out[0] = atomicAdd(&ws[0], 0.0f);
      }
    }
  }
}

extern "C" void kernel_launch(void* const* d_in, const int* in_sizes, int n_in,
                              void* d_out, int out_size, void* d_ws, size_t ws_size,
                              hipStream_t stream) {
  const float* pred = (const float*)d_in[0];
  const float* gt   = (const float*)d_in[1];
  float* out = (float*)d_out;
  float* ws  = (float*)d_ws;

  // tier selection depends only on ws_size (call-invariant) -> graph-safe
  if (ws_size >= WS_NEED_SGPR) {
    float4* gt4  = (float4*)(ws + PART_OFF);          // 64B-aligned
    float* partL = ws + PART_OFF + GT4_FLOATS;
    float* partA = partL + (size_t)NSPLIT * kB * kM;
    emd_prep_kernel<<<(kB * kN) / 256, 256, 0, stream>>>(gt, gt4);
    emd_partial_sgpr<<<NROWG * NSPLIT, BLOCKT, 0, stream>>>(pred, gt4, partL, partA);
    emd_combine_kernel<NSPLIT><<<CBLOCKS, CB, 0, stream>>>(partL, partA, ws, out);
  } else if (ws_size >= ws_need_old(4)) {
    float* partL = ws + PART_OFF;
    float* partA = partL + (size_t)4 * kB * kM;
    emd_partial_lds<4><<<NROWG * 4, BLOCKT, 0, stream>>>(pred, gt, partL, partA);
    emd_combine_kernel<4><<<CBLOCKS, CB, 0, stream>>>(partL, partA, ws, out);
  } else if (ws_size >= ws_need_old(2)) {
    float* partL = ws + PART_OFF;
    float* partA = partL + (size_t)2 * kB * kM;
    emd_partial_lds<2><<<NROWG * 2, BLOCKT, 0, stream>>>(pred, gt, partL, partA);
    emd_combine_kernel<2><<<CBLOCKS, CB, 0, stream>>>(partL, partA, ws, out);
  } else {
    emd_softmin_fallback<<<F_NBLOCKS, F_BLOCKT, 0, stream>>>(pred, gt, ws, out);
  }
}

// Round 10
// 98.082 us; speedup vs baseline: 1.2129x; 1.2129x over previous
//
#include <hip/hip_runtime.h>
#include <hip/hip_bf16.h>

#ifndef __has_builtin
#define __has_builtin(x) 0
#endif

#if __has_builtin(__builtin_amdgcn_exp2f)
#define FAST_EXP2(x) __builtin_amdgcn_exp2f(x)
#else
#define FAST_EXP2(x) exp2f(x)
#endif

#if __has_builtin(__builtin_amdgcn_sqrtf)
#define FAST_SQRT(x) __builtin_amdgcn_sqrtf(x)
#else
#define FAST_SQRT(x) sqrtf(x)
#endif

// Problem constants (fixed by setup_inputs): B=8, M=N=4096, C=3
constexpr int kB = 8;
constexpr int kM = 4096;
constexpr int kN = 4096;
// softmin: exp(-d/T) = exp2(-C2*d), T=0.1; work in ds = C2*d via C2^2-scaled d^2
constexpr float C2  = 14.426950408889634f;
constexpr float C22 = C2 * C2;
// harness re-poisons d_ws to 0xAA bytes before every launch (stated contract)
#define POISON_U32 0xAAAAAAAAu   // as float: -3.03e-13 (harmless accum base)

constexpr int RPL    = 4;                 // pred rows per lane
constexpr int GB     = 4;                 // gt points per batch
constexpr int BATCH  = RPL * GB;          // 16 independent chains per phase
constexpr int ROWS   = 64 * RPL;          // 256 rows per block
constexpr int WAVES  = 16;
constexpr int BLOCKT = 64 * WAVES;        // 1024 threads
constexpr int NROWG  = (kB * kM) / ROWS;  // 128 row groups
constexpr int NSPLIT = 4;                 // gt segments across blocks (512 blocks)
// ws layout (tier 1): [0]=accum [1]=ticket [16..]=gt4[kB*kN*4] then partials
constexpr int    PART_OFF  = 16;
constexpr size_t GT4_FLOATS = (size_t)kB * kN * 4;            // 131072
constexpr size_t ws_need_old(int ns) { return (size_t)(PART_OFF + 2 * ns * kB * kM) * 4; }
constexpr size_t WS_NEED_SGPR = (PART_OFF + GT4_FLOATS + (size_t)2 * NSPLIT * kB * kM) * 4;

// ---------------- phase 0: pack gt as (x,y,z, C2^2*|g|^2) ----------------
__global__ __launch_bounds__(256) void emd_prep_kernel(
    const float* __restrict__ gt, float4* __restrict__ gt4) {
  const int i = blockIdx.x * 256 + threadIdx.x;   // < kB*kN
  const float* p = gt + 3 * (size_t)i;
  float x = p[0], y = p[1], z = p[2];
  gt4[i] = make_float4(x, y, z, C22 * fmaf(x, x, fmaf(y, y, z * z)));
}

// ------- phase 1: SGPR gt, HW trans, BATCHED PHASES to force ILP -------
// R9 post-mortem: VGPR=32 -> compiler held ~2 of 16 "independent" chains in
// flight; dep latency (fma->sqrt->exp->fma) dominated. Explicit u[16]/ds[16]
// array phases force 16 live intermediates (VGPR ~80 < 128 cap) and issue
// the 16 sqrts / 16 exps back-to-back into the trans pipe.
__global__ __launch_bounds__(BLOCKT, 4) void emd_partial_sgpr(
    const float* __restrict__ pred, const float4* __restrict__ gt4,
    float* __restrict__ partL, float* __restrict__ partA) {
  constexpr int SEGN = kN / NSPLIT;     // 1024 gt points per block
  constexpr int NPC  = SEGN / WAVES;    // 64 gt points per wave
  __shared__ float red_l[WAVES][RPL][64];   // lane-stride 1: conflict-free
  __shared__ float red_a[WAVES][RPL][64];

  const int tid  = threadIdx.x;
  const int lane = tid & 63;
  const int wv   = tid >> 6;
  const int rg   = blockIdx.x / NSPLIT;   // row group
  const int seg  = blockIdx.x % NSPLIT;   // gt segment
  const int rbase = rg * ROWS;
  const int b     = rbase >> 12;          // 256 | 4096 so no batch straddle

  // RPL pred rows per lane (VGPR-resident coefficients)
  float nx[RPL], ny[RPL], nz[RPL], pq[RPL];
  const int m0 = (rbase & (kM - 1)) + lane;
#pragma unroll
  for (int r = 0; r < RPL; ++r) {
    const float* pp = pred + ((size_t)b * kM + m0 + r * 64) * 3;
    float x = pp[0], y = pp[1], z = pp[2];
    nx[r] = -2.0f * C22 * x;
    ny[r] = -2.0f * C22 * y;
    nz[r] = -2.0f * C22 * z;
    pq[r] = C22 * fmaf(x, x, fmaf(y, y, z * z));
  }

  // wave-uniform gt pointer: force wv uniform so the loads scalarize
  const int wvu = __builtin_amdgcn_readfirstlane(wv);
  const float4* __restrict__ gq =
      gt4 + (size_t)b * kN + (size_t)seg * SEGN + (size_t)wvu * NPC;

  // fixed-reference softmin accumulation (d>=0 so exp2(-ds) in (0,1])
  float l[RPL] = {};
  float a[RPL] = {};
  float4 c0 = gq[0], c1 = gq[1], c2 = gq[2], c3 = gq[3];
  for (int k = 0; k < NPC; k += GB) {
    const int kn = (k + GB < NPC) ? k + GB : 0;   // uniform select (dummy last)
    float4 n0 = gq[kn], n1 = gq[kn + 1], n2 = gq[kn + 2], n3 = gq[kn + 3];

    float u[BATCH];
    // phase A: 16 distance chains (pure full-rate fma, independent)
#define UCHAIN(G, j)                                                     \
    _Pragma("unroll")                                                    \
    for (int r = 0; r < RPL; ++r)                                        \
      u[(j)*RPL + r] = fmaf(nx[r], G.x,                                  \
                       fmaf(ny[r], G.y, fmaf(nz[r], G.z, G.w + pq[r])));
    UCHAIN(c0, 0) UCHAIN(c1, 1) UCHAIN(c2, 2) UCHAIN(c3, 3)
#undef UCHAIN
    // phase B: 16 sqrts back-to-back (trans pipe)
    float ds[BATCH];
#pragma unroll
    for (int i = 0; i < BATCH; ++i) ds[i] = FAST_SQRT(fmaxf(u[i], 0.0f));
    // phase C: 16 exps back-to-back (trans pipe); u[] reused for weights
#pragma unroll
    for (int i = 0; i < BATCH; ++i) u[i] = FAST_EXP2(-ds[i]);
    // phase D: accumulate
#pragma unroll
    for (int i = 0; i < BATCH; ++i) {
      const int r = i & (RPL - 1);
      l[r] += u[i];
      a[r] = fmaf(ds[i], u[i], a[r]);
    }
    c0 = n0; c1 = n1; c2 = n2; c3 = n3;
  }
#pragma unroll
  for (int r = 0; r < RPL; ++r) {
    red_l[wv][r][lane] = l[r];
    red_a[wv][r][lane] = a[r];
  }
  __syncthreads();

  // combine the 16 waves' chunks; one thread per (r, lane) row
  if (tid < 64 * RPL) {
    const int ln = tid & 63, r = tid >> 6;
    float lt = 0.f, at = 0.f;
#pragma unroll
    for (int c = 0; c < WAVES; ++c) { lt += red_l[c][r][ln]; at += red_a[c][r][ln]; }
    const int row = rbase + r * 64 + ln;
    partL[(size_t)seg * (kB * kM) + row] = lt;
    partA[(size_t)seg * (kB * kM) + row] = at;
  }
}

// ---------------- phase 2: per-row divide + global mean ----------------
constexpr int CB      = 512;
constexpr int CBLOCKS = (kB * kM) / CB;   // 64
template <int NSEG>
__global__ __launch_bounds__(CB) void emd_combine_kernel(
    const float* __restrict__ partL, const float* __restrict__ partA,
    float* __restrict__ ws, float* __restrict__ out) {
  const int row = blockIdx.x * CB + threadIdx.x;
  float lt = 0.f, at = 0.f;
#pragma unroll
  for (int s = 0; s < NSEG; ++s) {
    lt += partL[(size_t)s * (kB * kM) + row];
    at += partA[(size_t)s * (kB * kM) + row];
  }
  // at/lt = C2 * softmin-weighted dist; undo C2 and fold the 1/(B*M) mean
  float w = (at / lt) * (1.0f / (C2 * (float)(kB * kM)));
#pragma unroll
  for (int off = 32; off > 0; off >>= 1) w += __shfl_down(w, off, 64);
  __shared__ float sred[CB / 64];
  const int lane = threadIdx.x & 63, wv = threadIdx.x >> 6;
  if (lane == 0) sred[wv] = w;
  __syncthreads();
  if (threadIdx.x == 0) {
    float s = 0.f;
#pragma unroll
    for (int i = 0; i < CB / 64; ++i) s += sred[i];
    // ws[0] starts at poison float(0xAAAAAAAA) = -3.03e-13 (negligible)
    atomicAdd(&ws[0], s);
    __threadfence();
    unsigned t = atomicAdd((unsigned int*)(ws + 1), 1u);
    if (t == POISON_U32 + (unsigned)(CBLOCKS - 1)) {
      __threadfence();
      out[0] = atomicAdd(&ws[0], 0.0f);   // device-coherent read; fp32 output
    }
  }
}

// -------- tier-2 partial (R7 LDS path, proven 42.6 us) if ws too small --------
template <int NS>
__global__ __launch_bounds__(BLOCKT, 4) void emd_partial_lds(
    const float* __restrict__ pred, const float* __restrict__ gt,
    float* __restrict__ partL, float* __restrict__ partA) {
  constexpr int SEGN = kN / NS;
  constexpr int NPC  = SEGN / WAVES;
  __shared__ __align__(16) float4 g4[SEGN];
  __shared__ float red_l[WAVES][RPL][64];
  __shared__ float red_a[WAVES][RPL][64];
  const int tid = threadIdx.x, lane = tid & 63, wv = tid >> 6;
  const int rg = blockIdx.x / NS, seg = blockIdx.x % NS;
  const int rbase = rg * ROWS, b = rbase >> 12;
  const float* gtb = gt + ((size_t)b * kN + (size_t)seg * SEGN) * 3;
  for (int i = tid; i < SEGN; i += BLOCKT) {
    const float* p = gtb + 3 * i;
    float x = p[0], y = p[1], z = p[2];
    g4[i] = make_float4(x, y, z, C22 * fmaf(x, x, fmaf(y, y, z * z)));
  }
  float nx[RPL], ny[RPL], nz[RPL], pq[RPL];
  const int m0 = (rbase & (kM - 1)) + lane;
#pragma unroll
  for (int r = 0; r < RPL; ++r) {
    const float* pp = pred + ((size_t)b * kM + m0 + r * 64) * 3;
    float x = pp[0], y = pp[1], z = pp[2];
    nx[r] = -2.0f * C22 * x; ny[r] = -2.0f * C22 * y; nz[r] = -2.0f * C22 * z;
    pq[r] = C22 * fmaf(x, x, fmaf(y, y, z * z));
  }
  __syncthreads();
  float l[RPL] = {}, a[RPL] = {};
  const int n0 = wv * NPC;
  for (int n = n0; n < n0 + NPC; n += 4) {
    float4 G[4];
#pragma unroll
    for (int j = 0; j < 4; ++j) G[j] = g4[n + j];
#pragma unroll
    for (int j = 0; j < 4; ++j)
#pragma unroll
      for (int r = 0; r < RPL; ++r) {
        float u  = fmaf(nx[r], G[j].x,
                   fmaf(ny[r], G[j].y, fmaf(nz[r], G[j].z, G[j].w + pq[r])));
        float ds = FAST_SQRT(fmaxf(u, 0.0f));
        float p  = FAST_EXP2(-ds);
        l[r] += p; a[r] = fmaf(ds, p, a[r]);
      }
  }
#pragma unroll
  for (int r = 0; r < RPL; ++r) { red_l[wv][r][lane] = l[r]; red_a[wv][r][lane] = a[r]; }
  __syncthreads();
  if (tid < 64 * RPL) {
    const int ln = tid & 63, r = tid >> 6;
    float lt = 0.f, at = 0.f;
#pragma unroll
    for (int c = 0; c < WAVES; ++c) { lt += red_l[c][r][ln]; at += red_a[c][r][ln]; }
    const int row = rbase + r * 64 + ln;
    partL[(size_t)seg * (kB * kM) + row] = lt;
    partA[(size_t)seg * (kB * kM) + row] = at;
  }
}

// ---------------- tier-3 mono-kernel fallback (proven R3) ----------------
constexpr int F_CHUNKS = 16, F_BLOCKT = 64 * F_CHUNKS;
constexpr int F_NPC = kN / F_CHUNKS, F_NBLOCKS = (kB * kM) / 64;
__global__ __launch_bounds__(F_BLOCKT, 8) void emd_softmin_fallback(
    const float* __restrict__ pred, const float* __restrict__ gt,
    float* __restrict__ ws, float* __restrict__ out) {
  __shared__ __align__(16) float4 g4[kN];
  __shared__ float red_l[F_CHUNKS][64];
  __shared__ float red_a[F_CHUNKS][64];
  const int tid = threadIdx.x, lane = tid & 63, chunk = tid >> 6;
  const int rbase = blockIdx.x * 64, b = rbase >> 12, m = (rbase & (kM - 1)) + lane;
  const float* gtb = gt + (size_t)b * kN * 3;
  for (int i = tid; i < kN; i += F_BLOCKT) {
    const float* p = gtb + 3 * i;
    float x = p[0], y = p[1], z = p[2];
    g4[i] = make_float4(x, y, z, C22 * fmaf(x, x, fmaf(y, y, z * z)));
  }
  const float* pp = pred + ((size_t)b * kM + (size_t)m) * 3;
  const float px = pp[0], py = pp[1], pz = pp[2];
  const float nx = -2.0f * C22 * px, ny = -2.0f * C22 * py, nz = -2.0f * C22 * pz;
  const float pq = C22 * fmaf(px, px, fmaf(py, py, pz * pz));
  __syncthreads();
  float l0 = 0.f, l1 = 0.f, a0 = 0.f, a1 = 0.f;
  const int n0 = chunk * F_NPC;
#pragma unroll 2
  for (int n = n0; n < n0 + F_NPC; n += 2) {
    const float4 G0 = g4[n], G1 = g4[n + 1];
    { float u = fmaf(nx, G0.x, fmaf(ny, G0.y, fmaf(nz, G0.z, G0.w + pq)));
      float ds = FAST_SQRT(fmaxf(u, 0.f)); float p = FAST_EXP2(-ds);
      l0 += p; a0 = fmaf(ds, p, a0); }
    { float u = fmaf(nx, G1.x, fmaf(ny, G1.y, fmaf(nz, G1.z, G1.w + pq)));
      float ds = FAST_SQRT(fmaxf(u, 0.f)); float p = FAST_EXP2(-ds);
      l1 += p; a1 = fmaf(ds, p, a1); }
  }
  red_l[chunk][lane] = l0 + l1; red_a[chunk][lane] = a0 + a1;
  __syncthreads();
  if (tid < 64) {
    float lt = 0.f, at = 0.f;
#pragma unroll
    for (int c = 0; c < F_CHUNKS; ++c) { lt += red_l[c][tid]; at += red_a[c][tid]; }
    float w = (at / lt) * (1.0f / (C2 * (float)(kB * kM)));
#pragma unroll
    for (int off = 32; off > 0; off >>= 1) w += __shfl_down(w, off, 64);
    if (tid == 0) {
      atomicAdd(&ws[0], w);
      __threadfence();
      unsigned t = atomicAdd((unsigned int*)(ws + 1), 1u);
      if (t == POISON_U32 + (unsigned)(F_NBLOCKS - 1)) {
        __threadfence();
        out[0] = atomicAdd(&ws[0], 0.0f);
      }
    }
  }
}

extern "C" void kernel_launch(void* const* d_in, const int* in_sizes, int n_in,
                              void* d_out, int out_size, void* d_ws, size_t ws_size,
                              hipStream_t stream) {
  const float* pred = (const float*)d_in[0];
  const float* gt   = (const float*)d_in[1];
  float* out = (float*)d_out;
  float* ws  = (float*)d_ws;

  // tier selection depends only on ws_size (call-invariant) -> graph-safe
  if (ws_size >= WS_NEED_SGPR) {
    float4* gt4  = (float4*)(ws + PART_OFF);          // 64B-aligned
    float* partL = ws + PART_OFF + GT4_FLOATS;
    float* partA = partL + (size_t)NSPLIT * kB * kM;
    emd_prep_kernel<<<(kB * kN) / 256, 256, 0, stream>>>(gt, gt4);
    emd_partial_sgpr<<<NROWG * NSPLIT, BLOCKT, 0, stream>>>(pred, gt4, partL, partA);
    emd_combine_kernel<NSPLIT><<<CBLOCKS, CB, 0, stream>>>(partL, partA, ws, out);
  } else if (ws_size >= ws_need_old(4)) {
    float* partL = ws + PART_OFF;
    float* partA = partL + (size_t)4 * kB * kM;
    emd_partial_lds<4><<<NROWG * 4, BLOCKT, 0, stream>>>(pred, gt, partL, partA);
    emd_combine_kernel<4><<<CBLOCKS, CB, 0, stream>>>(partL, partA, ws, out);
  } else if (ws_size >= ws_need_old(2)) {
    float* partL = ws + PART_OFF;
    float* partA = partL + (size_t)2 * kB * kM;
    emd_partial_lds<2><<<NROWG * 2, BLOCKT, 0, stream>>>(pred, gt, partL, partA);
    emd_combine_kernel<2><<<CBLOCKS, CB, 0, stream>>>(partL, partA, ws, out);
  } else {
    emd_softmin_fallback<<<F_NBLOCKS, F_BLOCKT, 0, stream>>>(pred, gt, ws, out);
  }
}

// Round 11
// 96.770 us; speedup vs baseline: 1.2293x; 1.0136x over previous
//
#include <hip/hip_runtime.h>
#include <hip/hip_bf16.h>

#ifndef __has_builtin
#define __has_builtin(x) 0
#endif

#if __has_builtin(__builtin_amdgcn_exp2f)
#define FAST_EXP2(x) __builtin_amdgcn_exp2f(x)
#else
#define FAST_EXP2(x) exp2f(x)
#endif

#if __has_builtin(__builtin_amdgcn_sqrtf)
#define FAST_SQRT(x) __builtin_amdgcn_sqrtf(x)
#else
#define FAST_SQRT(x) sqrtf(x)
#endif

// scheduling fence: nothing may move across (forces phase materialization)
#if __has_builtin(__builtin_amdgcn_sched_barrier)
#define SCHED_FENCE() __builtin_amdgcn_sched_barrier(0)
#else
#define SCHED_FENCE() ((void)0)   // degrades to R10 behavior (43.8 us)
#endif

// Problem constants (fixed by setup_inputs): B=8, M=N=4096, C=3
constexpr int kB = 8;
constexpr int kM = 4096;
constexpr int kN = 4096;
// softmin: exp(-d/T) = exp2(-C2*d), T=0.1; work in ds = C2*d via C2^2-scaled d^2
constexpr float C2  = 14.426950408889634f;
constexpr float C22 = C2 * C2;
// harness re-poisons d_ws to 0xAA bytes before every launch (stated contract)
#define POISON_U32 0xAAAAAAAAu   // as float: -3.03e-13 (harmless accum base)

constexpr int RPL    = 4;                 // pred rows per lane
constexpr int GB     = 4;                 // gt points per batch
constexpr int BATCH  = RPL * GB;          // 16 independent chains per phase
constexpr int ROWS   = 64 * RPL;          // 256 rows per block
constexpr int WAVES  = 16;
constexpr int BLOCKT = 64 * WAVES;        // 1024 threads
constexpr int NROWG  = (kB * kM) / ROWS;  // 128 row groups
constexpr int NSPLIT = 4;                 // gt segments across blocks (512 blocks)
// ws layout (tier 1): [0]=accum [1]=ticket [16..]=gt4[kB*kN*4] then partials
constexpr int    PART_OFF  = 16;
constexpr size_t GT4_FLOATS = (size_t)kB * kN * 4;            // 131072
constexpr size_t ws_need_old(int ns) { return (size_t)(PART_OFF + 2 * ns * kB * kM) * 4; }
constexpr size_t WS_NEED_SGPR = (PART_OFF + GT4_FLOATS + (size_t)2 * NSPLIT * kB * kM) * 4;

// ---------------- phase 0: pack gt as (x,y,z, C2^2*|g|^2) ----------------
__global__ __launch_bounds__(256) void emd_prep_kernel(
    const float* __restrict__ gt, float4* __restrict__ gt4) {
  const int i = blockIdx.x * 256 + threadIdx.x;   // < kB*kN
  const float* p = gt + 3 * (size_t)i;
  float x = p[0], y = p[1], z = p[2];
  gt4[i] = make_float4(x, y, z, C22 * fmaf(x, x, fmaf(y, y, z * z)));
}

// ------- phase 1: SGPR gt, HW trans, sched_barrier-pinned ILP phases -------
// R10 post-mortem: explicit arrays alone don't force liveness (VGPR stayed 32;
// MachineScheduler re-interleaved the phases). sched_barrier(0) between phases
// pins the schedule: 16 live u's cross fence 1, 16 live ds's cross fences 2-3,
// and the 16 sqrts / 16 exps issue back-to-back into the trans pipe.
__global__ __launch_bounds__(BLOCKT, 4) void emd_partial_sgpr(
    const float* __restrict__ pred, const float4* __restrict__ gt4,
    float* __restrict__ partL, float* __restrict__ partA) {
  constexpr int SEGN = kN / NSPLIT;     // 1024 gt points per block
  constexpr int NPC  = SEGN / WAVES;    // 64 gt points per wave
  __shared__ float red_l[WAVES][RPL][64];   // lane-stride 1: conflict-free
  __shared__ float red_a[WAVES][RPL][64];

  const int tid  = threadIdx.x;
  const int lane = tid & 63;
  const int wv   = tid >> 6;
  const int rg   = blockIdx.x / NSPLIT;   // row group
  const int seg  = blockIdx.x % NSPLIT;   // gt segment
  const int rbase = rg * ROWS;
  const int b     = rbase >> 12;          // 256 | 4096 so no batch straddle

  // RPL pred rows per lane (VGPR-resident coefficients)
  float nx[RPL], ny[RPL], nz[RPL], pq[RPL];
  const int m0 = (rbase & (kM - 1)) + lane;
#pragma unroll
  for (int r = 0; r < RPL; ++r) {
    const float* pp = pred + ((size_t)b * kM + m0 + r * 64) * 3;
    float x = pp[0], y = pp[1], z = pp[2];
    nx[r] = -2.0f * C22 * x;
    ny[r] = -2.0f * C22 * y;
    nz[r] = -2.0f * C22 * z;
    pq[r] = C22 * fmaf(x, x, fmaf(y, y, z * z));
  }

  // wave-uniform gt pointer: force wv uniform so the loads scalarize
  const int wvu = __builtin_amdgcn_readfirstlane(wv);
  const float4* __restrict__ gq =
      gt4 + (size_t)b * kN + (size_t)seg * SEGN + (size_t)wvu * NPC;

  // fixed-reference softmin accumulation (d>=0 so exp2(-ds) in (0,1])
  float l[RPL] = {};
  float a[RPL] = {};
  float4 c0 = gq[0], c1 = gq[1], c2 = gq[2], c3 = gq[3];
  for (int k = 0; k < NPC; k += GB) {
    const int kn = (k + GB < NPC) ? k + GB : 0;   // uniform select (dummy last)
    float4 n0 = gq[kn], n1 = gq[kn + 1], n2 = gq[kn + 2], n3 = gq[kn + 3];

    // phase A: 16 distance chains (full-rate fma + clamp), all independent
    float u[BATCH];
#define UCHAIN(G, j)                                                     \
    _Pragma("unroll")                                                    \
    for (int r = 0; r < RPL; ++r)                                        \
      u[(j)*RPL + r] = fmaxf(fmaf(nx[r], G.x,                            \
                       fmaf(ny[r], G.y, fmaf(nz[r], G.z, G.w + pq[r]))), \
                       0.0f);
    UCHAIN(c0, 0) UCHAIN(c1, 1) UCHAIN(c2, 2) UCHAIN(c3, 3)
#undef UCHAIN
    SCHED_FENCE();
    // phase B: 16 sqrts back-to-back (trans pipe)
    float ds[BATCH];
#pragma unroll
    for (int i = 0; i < BATCH; ++i) ds[i] = FAST_SQRT(u[i]);
    SCHED_FENCE();
    // phase C: 16 exps back-to-back (trans pipe); u[] reused for weights
#pragma unroll
    for (int i = 0; i < BATCH; ++i) u[i] = FAST_EXP2(-ds[i]);
    SCHED_FENCE();
    // phase D: accumulate
#pragma unroll
    for (int i = 0; i < BATCH; ++i) {
      const int r = i & (RPL - 1);
      l[r] += u[i];
      a[r] = fmaf(ds[i], u[i], a[r]);
    }
    c0 = n0; c1 = n1; c2 = n2; c3 = n3;
  }
#pragma unroll
  for (int r = 0; r < RPL; ++r) {
    red_l[wv][r][lane] = l[r];
    red_a[wv][r][lane] = a[r];
  }
  __syncthreads();

  // combine the 16 waves' chunks; one thread per (r, lane) row
  if (tid < 64 * RPL) {
    const int ln = tid & 63, r = tid >> 6;
    float lt = 0.f, at = 0.f;
#pragma unroll
    for (int c = 0; c < WAVES; ++c) { lt += red_l[c][r][ln]; at += red_a[c][r][ln]; }
    const int row = rbase + r * 64 + ln;
    partL[(size_t)seg * (kB * kM) + row] = lt;
    partA[(size_t)seg * (kB * kM) + row] = at;
  }
}

// ---------------- phase 2: per-row divide + global mean ----------------
constexpr int CB      = 512;
constexpr int CBLOCKS = (kB * kM) / CB;   // 64
template <int NSEG>
__global__ __launch_bounds__(CB) void emd_combine_kernel(
    const float* __restrict__ partL, const float* __restrict__ partA,
    float* __restrict__ ws, float* __restrict__ out) {
  const int row = blockIdx.x * CB + threadIdx.x;
  float lt = 0.f, at = 0.f;
#pragma unroll
  for (int s = 0; s < NSEG; ++s) {
    lt += partL[(size_t)s * (kB * kM) + row];
    at += partA[(size_t)s * (kB * kM) + row];
  }
  // at/lt = C2 * softmin-weighted dist; undo C2 and fold the 1/(B*M) mean
  float w = (at / lt) * (1.0f / (C2 * (float)(kB * kM)));
#pragma unroll
  for (int off = 32; off > 0; off >>= 1) w += __shfl_down(w, off, 64);
  __shared__ float sred[CB / 64];
  const int lane = threadIdx.x & 63, wv = threadIdx.x >> 6;
  if (lane == 0) sred[wv] = w;
  __syncthreads();
  if (threadIdx.x == 0) {
    float s = 0.f;
#pragma unroll
    for (int i = 0; i < CB / 64; ++i) s += sred[i];
    // ws[0] starts at poison float(0xAAAAAAAA) = -3.03e-13 (negligible)
    atomicAdd(&ws[0], s);
    __threadfence();
    unsigned t = atomicAdd((unsigned int*)(ws + 1), 1u);
    if (t == POISON_U32 + (unsigned)(CBLOCKS - 1)) {
      __threadfence();
      out[0] = atomicAdd(&ws[0], 0.0f);   // device-coherent read; fp32 output
    }
  }
}

// -------- tier-2 partial (R7 LDS path, proven 42.6 us) if ws too small --------
template <int NS>
__global__ __launch_bounds__(BLOCKT, 4) void emd_partial_lds(
    const float* __restrict__ pred, const float* __restrict__ gt,
    float* __restrict__ partL, float* __restrict__ partA) {
  constexpr int SEGN = kN / NS;
  constexpr int NPC  = SEGN / WAVES;
  __shared__ __align__(16) float4 g4[SEGN];
  __shared__ float red_l[WAVES][RPL][64];
  __shared__ float red_a[WAVES][RPL][64];
  const int tid = threadIdx.x, lane = tid & 63, wv = tid >> 6;
  const int rg = blockIdx.x / NS, seg = blockIdx.x % NS;
  const int rbase = rg * ROWS, b = rbase >> 12;
  const float* gtb = gt + ((size_t)b * kN + (size_t)seg * SEGN) * 3;
  for (int i = tid; i < SEGN; i += BLOCKT) {
    const float* p = gtb + 3 * i;
    float x = p[0], y = p[1], z = p[2];
    g4[i] = make_float4(x, y, z, C22 * fmaf(x, x, fmaf(y, y, z * z)));
  }
  float nx[RPL], ny[RPL], nz[RPL], pq[RPL];
  const int m0 = (rbase & (kM - 1)) + lane;
#pragma unroll
  for (int r = 0; r < RPL; ++r) {
    const float* pp = pred + ((size_t)b * kM + m0 + r * 64) * 3;
    float x = pp[0], y = pp[1], z = pp[2];
    nx[r] = -2.0f * C22 * x; ny[r] = -2.0f * C22 * y; nz[r] = -2.0f * C22 * z;
    pq[r] = C22 * fmaf(x, x, fmaf(y, y, z * z));
  }
  __syncthreads();
  float l[RPL] = {}, a[RPL] = {};
  const int n0 = wv * NPC;
  for (int n = n0; n < n0 + NPC; n += 4) {
    float4 G[4];
#pragma unroll
    for (int j = 0; j < 4; ++j) G[j] = g4[n + j];
#pragma unroll
    for (int j = 0; j < 4; ++j)
#pragma unroll
      for (int r = 0; r < RPL; ++r) {
        float u  = fmaf(nx[r], G[j].x,
                   fmaf(ny[r], G[j].y, fmaf(nz[r], G[j].z, G[j].w + pq[r])));
        float ds = FAST_SQRT(fmaxf(u, 0.0f));
        float p  = FAST_EXP2(-ds);
        l[r] += p; a[r] = fmaf(ds, p, a[r]);
      }
  }
#pragma unroll
  for (int r = 0; r < RPL; ++r) { red_l[wv][r][lane] = l[r]; red_a[wv][r][lane] = a[r]; }
  __syncthreads();
  if (tid < 64 * RPL) {
    const int ln = tid & 63, r = tid >> 6;
    float lt = 0.f, at = 0.f;
#pragma unroll
    for (int c = 0; c < WAVES; ++c) { lt += red_l[c][r][ln]; at += red_a[c][r][ln]; }
    const int row = rbase + r * 64 + ln;
    partL[(size_t)seg * (kB * kM) + row] = lt;
    partA[(size_t)seg * (kB * kM) + row] = at;
  }
}

// ---------------- tier-3 mono-kernel fallback (proven R3) ----------------
constexpr int F_CHUNKS = 16, F_BLOCKT = 64 * F_CHUNKS;
constexpr int F_NPC = kN / F_CHUNKS, F_NBLOCKS = (kB * kM) / 64;
__global__ __launch_bounds__(F_BLOCKT, 8) void emd_softmin_fallback(
    const float* __restrict__ pred, const float* __restrict__ gt,
    float* __restrict__ ws, float* __restrict__ out) {
  __shared__ __align__(16) float4 g4[kN];
  __shared__ float red_l[F_CHUNKS][64];
  __shared__ float red_a[F_CHUNKS][64];
  const int tid = threadIdx.x, lane = tid & 63, chunk = tid >> 6;
  const int rbase = blockIdx.x * 64, b = rbase >> 12, m = (rbase & (kM - 1)) + lane;
  const float* gtb = gt + (size_t)b * kN * 3;
  for (int i = tid; i < kN; i += F_BLOCKT) {
    const float* p = gtb + 3 * i;
    float x = p[0], y = p[1], z = p[2];
    g4[i] = make_float4(x, y, z, C22 * fmaf(x, x, fmaf(y, y, z * z)));
  }
  const float* pp = pred + ((size_t)b * kM + (size_t)m) * 3;
  const float px = pp[0], py = pp[1], pz = pp[2];
  const float nx = -2.0f * C22 * px, ny = -2.0f * C22 * py, nz = -2.0f * C22 * pz;
  const float pq = C22 * fmaf(px, px, fmaf(py, py, pz * pz));
  __syncthreads();
  float l0 = 0.f, l1 = 0.f, a0 = 0.f, a1 = 0.f;
  const int n0 = chunk * F_NPC;
#pragma unroll 2
  for (int n = n0; n < n0 + F_NPC; n += 2) {
    const float4 G0 = g4[n], G1 = g4[n + 1];
    { float u = fmaf(nx, G0.x, fmaf(ny, G0.y, fmaf(nz, G0.z, G0.w + pq)));
      float ds = FAST_SQRT(fmaxf(u, 0.f)); float p = FAST_EXP2(-ds);
      l0 += p; a0 = fmaf(ds, p, a0); }
    { float u = fmaf(nx, G1.x, fmaf(ny, G1.y, fmaf(nz, G1.z, G1.w + pq)));
      float ds = FAST_SQRT(fmaxf(u, 0.f)); float p = FAST_EXP2(-ds);
      l1 += p; a1 = fmaf(ds, p, a1); }
  }
  red_l[chunk][lane] = l0 + l1; red_a[chunk][lane] = a0 + a1;
  __syncthreads();
  if (tid < 64) {
    float lt = 0.f, at = 0.f;
#pragma unroll
    for (int c = 0; c < F_CHUNKS; ++c) { lt += red_l[c][tid]; at += red_a[c][tid]; }
    float w = (at / lt) * (1.0f / (C2 * (float)(kB * kM)));
#pragma unroll
    for (int off = 32; off > 0; off >>= 1) w += __shfl_down(w, off, 64);
    if (tid == 0) {
      atomicAdd(&ws[0], w);
      __threadfence();
      unsigned t = atomicAdd((unsigned int*)(ws + 1), 1u);
      if (t == POISON_U32 + (unsigned)(F_NBLOCKS - 1)) {
        __threadfence();
        out[0] = atomicAdd(&ws[0], 0.0f);
      }
    }
  }
}

extern "C" void kernel_launch(void* const* d_in, const int* in_sizes, int n_in,
                              void* d_out, int out_size, void* d_ws, size_t ws_size,
                              hipStream_t stream) {
  const float* pred = (const float*)d_in[0];
  const float* gt   = (const float*)d_in[1];
  float* out = (float*)d_out;
  float* ws  = (float*)d_ws;

  // tier selection depends only on ws_size (call-invariant) -> graph-safe
  if (ws_size >= WS_NEED_SGPR) {
    float4* gt4  = (float4*)(ws + PART_OFF);          // 64B-aligned
    float* partL = ws + PART_OFF + GT4_FLOATS;
    float* partA = partL + (size_t)NSPLIT * kB * kM;
    emd_prep_kernel<<<(kB * kN) / 256, 256, 0, stream>>>(gt, gt4);
    emd_partial_sgpr<<<NROWG * NSPLIT, BLOCKT, 0, stream>>>(pred, gt4, partL, partA);
    emd_combine_kernel<NSPLIT><<<CBLOCKS, CB, 0, stream>>>(partL, partA, ws, out);
  } else if (ws_size >= ws_need_old(4)) {
    float* partL = ws + PART_OFF;
    float* partA = partL + (size_t)4 * kB * kM;
    emd_partial_lds<4><<<NROWG * 4, BLOCKT, 0, stream>>>(pred, gt, partL, partA);
    emd_combine_kernel<4><<<CBLOCKS, CB, 0, stream>>>(partL, partA, ws, out);
  } else if (ws_size >= ws_need_old(2)) {
    float* partL = ws + PART_OFF;
    float* partA = partL + (size_t)2 * kB * kM;
    emd_partial_lds<2><<<NROWG * 2, BLOCKT, 0, stream>>>(pred, gt, partL, partA);
    emd_combine_kernel<2><<<CBLOCKS, CB, 0, stream>>>(partL, partA, ws, out);
  } else {
    emd_softmin_fallback<<<F_NBLOCKS, F_BLOCKT, 0, stream>>>(pred, gt, ws, out);
  }
}